// Round 3
// baseline (598.278 us; speedup 1.0000x reference)
//
#include <hip/hip_runtime.h>
#include <hip/hip_bf16.h>
#include <hip/hip_cooperative_groups.h>
#include <cstdint>

namespace cg = cooperative_groups;

#define VOCAB 4096
#define ORDER 4
#define FAN   16388      // ORDER * (VOCAB + 1)
#define NL    2048
#define NPOS  16384      // B * L
#define NCT   129        // ceil(FAN/128)
#define NVT   32         // VOCAB/128
#define NTILE 4128       // NCT * NVT
#define NBLK  512        // persistent blocks (2 per CU)
#define TILE_LDS (128 * 129 * 4)   // 66048 B

typedef float        f4 __attribute__((ext_vector_type(4)));
typedef unsigned int u4 __attribute__((ext_vector_type(4)));
typedef unsigned int u2 __attribute__((ext_vector_type(2)));

static __device__ __forceinline__ unsigned short f2bf(float f)
{
    __hip_bfloat16 h = __float2bfloat16(f);
    unsigned short r;
    __builtin_memcpy(&r, &h, 2);
    return r;
}

// ---------------------------------------------------------------------------
// Fused cooperative kernel: phase A transposes W -> bf16 Wt (persistent
// 128x128 tiles), grid.sync(), phase B gathers 32 positions per block.
//   - one ~300us dispatch => real rocprof counters for our code
//   - bias preloaded into 16 regs once, reused for all 32 positions
// ---------------------------------------------------------------------------
__global__ __launch_bounds__(256) void k_fused(
    const int* __restrict__ idx, const float* __restrict__ W,
    const float* __restrict__ bias, float* __restrict__ out,
    unsigned short* __restrict__ Wt)
{
    extern __shared__ float tile[];           // [128][129]
    const int b   = blockIdx.x;               // 0..511
    const int tid = threadIdx.x;

    // ================= phase A: transpose =================
    {
        const int t0 = (b * NTILE) / NBLK;    // 8 or 9 tiles per block
        const int t1 = ((b + 1) * NTILE) / NBLK;

        const int cq  = (tid & 31) * 4;       // 0..124
        const int vr  = tid >> 5;             // 0..7
        const int pth = (tid & 15) * 8;       // v offset 0..120
        const int cb  = tid >> 4;             // 0..15

        for (int t = t0; t < t1; ++t) {
            const int vt = t / NCT;           // fixed v-range, sweep c: W rows
            const int ct = t - vt * NCT;      // read in ascending 512-B steps
            const int v0 = vt * 128;
            const int c0 = ct * 128;
            const bool cvalid = (c0 + cq) < FAN;   // FAN%4==0 -> whole f4 ok

            #pragma unroll
            for (int i = 0; i < 16; ++i) {
                const int v = vr + 8 * i;
                if (cvalid) {
                    const f4 f = __builtin_nontemporal_load(
                        (const f4*)(W + (size_t)(v0 + v) * FAN + (c0 + cq)));
                    tile[v * 129 + cq + 0] = f.x;
                    tile[v * 129 + cq + 1] = f.y;
                    tile[v * 129 + cq + 2] = f.z;
                    tile[v * 129 + cq + 3] = f.w;
                }
            }
            __syncthreads();

            #pragma unroll
            for (int i = 0; i < 8; ++i) {
                const int cl = cb + 16 * i;   // 0..127
                const int c  = c0 + cl;
                if (c < FAN) {
                    unsigned short s[8];
                    #pragma unroll
                    for (int j = 0; j < 8; ++j)
                        s[j] = f2bf(tile[(pth + j) * 129 + cl]);  // 4-way, non-critical
                    u4 pk;
                    pk.x = (unsigned)s[0] | ((unsigned)s[1] << 16);
                    pk.y = (unsigned)s[2] | ((unsigned)s[3] << 16);
                    pk.z = (unsigned)s[4] | ((unsigned)s[5] << 16);
                    pk.w = (unsigned)s[6] | ((unsigned)s[7] << 16);
                    *(u4*)(Wt + (size_t)c * VOCAB + v0 + pth) = pk;
                }
            }
            __syncthreads();                  // tile reused next iteration
        }
    }

    cg::this_grid().sync();                   // Wt complete

    // ================= phase B: gather =================
    {
        const int j4 = tid * 4;               // this thread's 4-v slice per seg

        f4 bv[4];
        #pragma unroll
        for (int s = 0; s < 4; ++s)
            bv[s] = *(const f4*)(bias + s * 1024 + j4);

        const int bb   = b >> 6;              // batch row (32 pos per block, 2048/32=64 blocks/row)
        const int lba  = (b * 32) & (NL - 1); // base l within row
        const int* row = idx + bb * NL;
        const char* Wb = (const char*)Wt;

        for (int gi = 0; gi < 8; ++gi) {
            const int l0 = lba + gi * 4;
            unsigned off[4][ORDER];
            #pragma unroll
            for (int p = 0; p < 4; ++p) {
                #pragma unroll
                for (int k = 0; k < ORDER; ++k) {
                    const int s   = ORDER - 1 - k;
                    const int lp  = l0 + p;
                    const int tok = (lp >= s) ? row[lp - s] : VOCAB;   // pad
                    off[p][k] = (unsigned)(((size_t)(k * (VOCAB + 1) + tok) * VOCAB) * 2u);
                }
            }

            float* o = out + ((size_t)bb * NL + l0) * VOCAB;

            #pragma unroll
            for (int seg = 0; seg < 4; ++seg) {
                const int v    = seg * 1024 + j4;
                const int voff = v * 2;

                u2 wv[4][ORDER];
                #pragma unroll
                for (int p = 0; p < 4; ++p)
                    #pragma unroll
                    for (int k = 0; k < ORDER; ++k)
                        wv[p][k] = *(const u2*)(Wb + off[p][k] + voff);

                #pragma unroll
                for (int p = 0; p < 4; ++p) {
                    float a0 = bv[seg].x, a1 = bv[seg].y,
                          a2 = bv[seg].z, a3 = bv[seg].w;
                    #pragma unroll
                    for (int k = 0; k < ORDER; ++k) {
                        const unsigned lo = wv[p][k].x, hi = wv[p][k].y;
                        a0 += __uint_as_float(lo << 16);
                        a1 += __uint_as_float(lo & 0xFFFF0000u);
                        a2 += __uint_as_float(hi << 16);
                        a3 += __uint_as_float(hi & 0xFFFF0000u);
                    }
                    f4 sv; sv.x = a0; sv.y = a1; sv.z = a2; sv.w = a3;
                    __builtin_nontemporal_store(sv, (f4*)(o + (size_t)p * VOCAB + v));
                }
            }
        }
    }
}

// ---------------------------------------------------------------------------
// Fallback pass 1 (r1, measured best standalone): 128x128 tiled transpose.
// ---------------------------------------------------------------------------
__global__ __launch_bounds__(512) void k_transpose_bf16(
    const float* __restrict__ W, unsigned short* __restrict__ Wt)
{
    __shared__ float tile[128][129];
    const int c0 = blockIdx.x * 128;
    const int v0 = blockIdx.y * 128;

    const int cq = (threadIdx.x & 31) * 4;
    const int vr = threadIdx.x >> 5;
    const bool cvalid = (c0 + cq) < FAN;

    #pragma unroll
    for (int i = 0; i < 8; ++i) {
        const int v = vr + 16 * i;
        if (cvalid) {
            const f4 f = __builtin_nontemporal_load(
                (const f4*)(W + (size_t)(v0 + v) * FAN + (c0 + cq)));
            tile[v][cq + 0] = f.x;
            tile[v][cq + 1] = f.y;
            tile[v][cq + 2] = f.z;
            tile[v][cq + 3] = f.w;
        }
    }
    __syncthreads();

    const int p  = (threadIdx.x & 15) * 8;
    const int cb = threadIdx.x >> 4;

    #pragma unroll
    for (int i = 0; i < 4; ++i) {
        const int cl = cb + 32 * i;
        const int c  = c0 + cl;
        if (c < FAN) {
            unsigned short s[8];
            #pragma unroll
            for (int j = 0; j < 8; ++j)
                s[j] = f2bf(tile[p + j][cl]);
            u4 pk;
            pk.x = (unsigned)s[0] | ((unsigned)s[1] << 16);
            pk.y = (unsigned)s[2] | ((unsigned)s[3] << 16);
            pk.z = (unsigned)s[4] | ((unsigned)s[5] << 16);
            pk.w = (unsigned)s[6] | ((unsigned)s[7] << 16);
            *(u4*)(Wt + (size_t)c * VOCAB + v0 + p) = pk;
        }
    }
}

// ---------------------------------------------------------------------------
// Fallback pass 2 (r2): 4 positions per block.
// ---------------------------------------------------------------------------
__global__ __launch_bounds__(256) void k_gather4(
    const int* __restrict__ idx, const unsigned short* __restrict__ Wt,
    const float* __restrict__ bias, float* __restrict__ out)
{
    const int pp = blockIdx.x * 4;
    const int bb = pp >> 11;
    const int l0 = pp & (NL - 1);
    const int* row = idx + bb * NL;

    unsigned off[4][ORDER];
    #pragma unroll
    for (int p = 0; p < 4; ++p) {
        #pragma unroll
        for (int k = 0; k < ORDER; ++k) {
            const int s   = ORDER - 1 - k;
            const int lp  = l0 + p;
            const int tok = (lp >= s) ? row[lp - s] : VOCAB;
            off[p][k] = (unsigned)(((size_t)(k * (VOCAB + 1) + tok) * VOCAB) * 2u);
        }
    }

    const char* Wb = (const char*)Wt;
    float* o = out + (size_t)pp * VOCAB;
    const int j4 = threadIdx.x * 4;

    #pragma unroll
    for (int seg = 0; seg < 4; ++seg) {
        const int v    = seg * 1024 + j4;
        const int voff = v * 2;
        const f4 bvv = *(const f4*)(bias + v);

        u2 wv[4][ORDER];
        #pragma unroll
        for (int p = 0; p < 4; ++p)
            #pragma unroll
            for (int k = 0; k < ORDER; ++k)
                wv[p][k] = *(const u2*)(Wb + off[p][k] + voff);

        #pragma unroll
        for (int p = 0; p < 4; ++p) {
            float a0 = bvv.x, a1 = bvv.y, a2 = bvv.z, a3 = bvv.w;
            #pragma unroll
            for (int k = 0; k < ORDER; ++k) {
                const unsigned lo = wv[p][k].x, hi = wv[p][k].y;
                a0 += __uint_as_float(lo << 16);
                a1 += __uint_as_float(lo & 0xFFFF0000u);
                a2 += __uint_as_float(hi << 16);
                a3 += __uint_as_float(hi & 0xFFFF0000u);
            }
            f4 sv; sv.x = a0; sv.y = a1; sv.z = a2; sv.w = a3;
            __builtin_nontemporal_store(sv, (f4*)(o + (size_t)p * VOCAB + v));
        }
    }
}

// ---------------------------------------------------------------------------
// Fallback (ws too small): direct strided reads from W.  Correct, slower.
// ---------------------------------------------------------------------------
__global__ __launch_bounds__(256) void k_direct(
    const int* __restrict__ idx, const float* __restrict__ W,
    const float* __restrict__ bias, float* __restrict__ out)
{
    const int pos = blockIdx.x;
    const int bb  = pos >> 11;
    const int ll  = pos & (NL - 1);
    const int* row = idx + bb * NL;

    int off[ORDER];
    #pragma unroll
    for (int k = 0; k < ORDER; ++k) {
        const int s   = ORDER - 1 - k;
        const int tok = (ll >= s) ? row[ll - s] : VOCAB;
        off[k] = k * (VOCAB + 1) + tok;
    }

    float* o = out + (size_t)pos * VOCAB;
    for (int v = threadIdx.x; v < VOCAB; v += 256) {
        const float* wr = W + (size_t)v * FAN;
        o[v] = bias[v] + wr[off[0]] + wr[off[1]] + wr[off[2]] + wr[off[3]];
    }
}

// ---------------------------------------------------------------------------
extern "C" void kernel_launch(void* const* d_in, const int* in_sizes, int n_in,
                              void* d_out, int out_size, void* d_ws, size_t ws_size,
                              hipStream_t stream)
{
    const int*   idx  = (const int*)d_in[0];
    const float* W    = (const float*)d_in[1];
    const float* bias = (const float*)d_in[2];
    float*       out  = (float*)d_out;

    const size_t wt_bytes = (size_t)FAN * VOCAB * 2;   // 134.25 MB

    if (ws_size >= wt_bytes) {
        unsigned short* Wt = (unsigned short*)d_ws;

        static int coop_ok = -1;
        if (coop_ok < 0) {
            int dev = 0;
            hipGetDevice(&dev);
            int sup = 0;
            hipDeviceGetAttribute(&sup, hipDeviceAttributeCooperativeLaunch, dev);
            const hipError_t ea = hipFuncSetAttribute(
                (const void*)k_fused,
                hipFuncAttributeMaxDynamicSharedMemorySize, TILE_LDS);
            coop_ok = (sup && ea == hipSuccess) ? 1 : 0;
        }

        bool done = false;
        if (coop_ok) {
            void* args[] = {(void*)&idx, (void*)&W, (void*)&bias,
                            (void*)&out, (void*)&Wt};
            const hipError_t e = hipLaunchCooperativeKernel(
                (const void*)k_fused, dim3(NBLK), dim3(256),
                args, TILE_LDS, stream);
            if (e == hipSuccess) done = true; else coop_ok = 0;
        }

        if (!done) {
            dim3 g1((FAN + 127) / 128, VOCAB / 128);
            k_transpose_bf16<<<g1, 512, 0, stream>>>(W, Wt);
            k_gather4<<<NPOS / 4, 256, 0, stream>>>(idx, Wt, bias, out);
        }
    } else {
        k_direct<<<NPOS, 256, 0, stream>>>(idx, W, bias, out);
    }
}